// Round 10
// baseline (310.182 us; speedup 1.0000x reference)
//
#include <hip/hip_runtime.h>
#include <hip/hip_bf16.h>

#define N_SRC 50000
#define N_DST 10000
#define KNBR  32
#define IN_F  256
#define OUT_F 128
#define LDIM  10
#define ATTN_OUT 1024
#define NB_BIG  782   // ceil(50000/64)
#define NB_SELF 157   // ceil(10000/64)

// Diagnostic repeat factors (idempotent re-execution; outputs identical).
// Purpose: push each phase's single dispatch above the ~42us harness fills so
// all three appear in the top-5 rocprof rows with full counters.
#define REP_PREP 24
#define REP_GEMM 3
#define REP_ATTN 4

using f32x4 = __attribute__((ext_vector_type(4))) float;
using s16x8 = __attribute__((ext_vector_type(8))) short;

// Output layout (floats): rst (N_DST*128) | cent_l (N_DST*10) | labels_ori[:N_DST] (N_DST*10)
#define OUT_CENT (N_DST*OUT_F)
#define OUT_LORI (N_DST*OUT_F + N_DST*LDIM)

// Workspace float offsets
#define WS_WCOMB 0                                   // 128 floats
#define WS_BN    128                                 // 32768 ushort
#define WS_BS    (128 + 16384)                       // 32768 ushort
#define WS_HSRC  (128 + 32768)                       // N_SRC*128 ushort
#define WS_SELF0 (WS_HSRC + (N_SRC*OUT_F/2))         // N_DST*128 floats
#define WS_SCORE (WS_SELF0 + N_DST*OUT_F)            // N_SRC floats

__device__ __forceinline__ ushort f2bf(float x) {
  __hip_bfloat16 h = __float2bfloat16(x);
  return *reinterpret_cast<ushort*>(&h);
}

__device__ __forceinline__ void unpack8(uint4 hv, float* o) {
  o[0] = __uint_as_float(hv.x << 16);
  o[1] = __uint_as_float(hv.x & 0xffff0000u);
  o[2] = __uint_as_float(hv.y << 16);
  o[3] = __uint_as_float(hv.y & 0xffff0000u);
  o[4] = __uint_as_float(hv.z << 16);
  o[5] = __uint_as_float(hv.z & 0xffff0000u);
  o[6] = __uint_as_float(hv.w << 16);
  o[7] = __uint_as_float(hv.w & 0xffff0000u);
}

// ---------------------------------------------------------------------------
// prep (R5 body, REP-wrapped)
// ---------------------------------------------------------------------------
__global__ __launch_bounds__(256) void prep_kernel(
    const float* __restrict__ W_attn, const float* __restrict__ fW,
    const float* __restrict__ W_neigh, const float* __restrict__ W_self,
    float* __restrict__ w_comb, ushort* __restrict__ Bn, ushort* __restrict__ Bs) {
  const int b = blockIdx.x;
  const int t = threadIdx.x;
  __shared__ float red[256];
#pragma unroll 1
  for (int rep = 0; rep < REP_PREP; ++rep) {
    if (b < 128) {
      float s = 0.f;
#pragma unroll
      for (int i = 0; i < 4; ++i) {
        int o = t + i * 256;
        s += W_attn[(size_t)b * ATTN_OUT + o] * fW[o];
      }
      red[t] = s;
      __syncthreads();
      for (int st = 128; st > 0; st >>= 1) {
        if (t < st) red[t] += red[t + st];
        __syncthreads();
      }
      if (t == 0) w_comb[b] = red[0];
      __syncthreads();
    } else if (b < 256) {
      int k = 2 * (b - 128) + (t >> 7);
      int n = t & 127;
      Bn[(k >> 3) * 1024 + n * 8 + (k & 7)] = f2bf(W_neigh[(size_t)k * OUT_F + n]);
    } else {
      int k = 2 * (b - 256) + (t >> 7);
      int n = t & 127;
      Bs[(k >> 3) * 1024 + n * 8 + (k & 7)] = f2bf(W_self[(size_t)k * OUT_F + n]);
    }
    asm volatile("" ::: "memory");
  }
}

// ---------------------------------------------------------------------------
// R5 GEMM body (64-row tile, wave=16 rows, batched A loads, no LDS).
// ---------------------------------------------------------------------------
template<bool OUT_BF16>
__device__ __forceinline__ void gemm_body(
    const float* __restrict__ A, const ushort* __restrict__ Bp,
    const float* __restrict__ bias, const float* __restrict__ w_comb,
    void* __restrict__ C, float* __restrict__ score_f, int M, int m0) {
  const int t = threadIdx.x;
  const int wv = t >> 6, ln = t & 63;
  const int dg = ln & 15, kg = ln >> 4;
  int r = m0 + wv * 16 + dg;
  r = r < M ? r : M - 1;
  const float* arow = &A[(size_t)r * IN_F];

  s16x8 afr[8];
#pragma unroll
  for (int half = 0; half < 2; ++half) {
    f32x4 araw[8];
#pragma unroll
    for (int k0 = 0; k0 < 4; ++k0) {
      const f32x4* ap = (const f32x4*)&arow[(half * 4 + k0) * 32 + kg * 8];
      araw[2 * k0]     = ap[0];
      araw[2 * k0 + 1] = ap[1];
    }
#pragma unroll
    for (int k0 = 0; k0 < 4; ++k0) {
      s16x8 f;
      f[0] = (short)f2bf(araw[2*k0][0]); f[1] = (short)f2bf(araw[2*k0][1]);
      f[2] = (short)f2bf(araw[2*k0][2]); f[3] = (short)f2bf(araw[2*k0][3]);
      f[4] = (short)f2bf(araw[2*k0+1][0]); f[5] = (short)f2bf(araw[2*k0+1][1]);
      f[6] = (short)f2bf(araw[2*k0+1][2]); f[7] = (short)f2bf(araw[2*k0+1][3]);
      afr[half * 4 + k0] = f;
    }
  }

  f32x4 acc[8];
#pragma unroll
  for (int ct = 0; ct < 8; ++ct) acc[ct] = (f32x4){0.f, 0.f, 0.f, 0.f};
#pragma unroll
  for (int k0 = 0; k0 < 8; ++k0) {
    const ushort* bb = Bp + (k0 * 4 + kg) * 1024 + dg * 8;
#pragma unroll
    for (int ct = 0; ct < 8; ++ct) {
      s16x8 bfr = *reinterpret_cast<const s16x8*>(bb + ct * 128);
      acc[ct] = __builtin_amdgcn_mfma_f32_16x16x32_bf16(afr[k0], bfr, acc[ct], 0, 0, 0);
    }
  }

  float sc[4] = {0.f, 0.f, 0.f, 0.f};
#pragma unroll
  for (int ct = 0; ct < 8; ++ct) {
    int col = ct * 16 + dg;
    float bb = bias[col];
    float wc = OUT_BF16 ? w_comb[col] : 0.f;
#pragma unroll
    for (int e = 0; e < 4; ++e) {
      int rr = m0 + wv * 16 + kg * 4 + e;
      float v = acc[ct][e] + bb;
      if (OUT_BF16) {
        sc[e] = fmaf(fmaxf(v, 0.1f * v), wc, sc[e]);
        if (rr < M) ((ushort*)C)[(size_t)rr * OUT_F + col] = f2bf(v);
      } else {
        if (rr < M) ((float*)C)[(size_t)rr * OUT_F + col] = v;
      }
    }
  }
  if (OUT_BF16) {
#pragma unroll
    for (int s = 1; s < 16; s <<= 1) {
#pragma unroll
      for (int e = 0; e < 4; ++e) sc[e] += __shfl_xor(sc[e], s);
    }
    if (dg == 0) {
#pragma unroll
      for (int e = 0; e < 4; ++e) {
        int rr = m0 + wv * 16 + kg * 4 + e;
        if (rr < M) score_f[rr] = sc[e];
      }
    }
  }
}

__global__ __launch_bounds__(256, 4) void fused_gemm(
    const float* __restrict__ A,
    const ushort* __restrict__ Bn, const ushort* __restrict__ Bs,
    const float* __restrict__ bias_n, const float* __restrict__ bias_s,
    const float* __restrict__ w_comb,
    ushort* __restrict__ hsrc, float* __restrict__ self0, float* __restrict__ score_f) {
#pragma unroll 1
  for (int rep = 0; rep < REP_GEMM; ++rep) {
    if (blockIdx.x < NB_BIG)
      gemm_body<true>(A, Bn, bias_n, w_comb, (void*)hsrc, score_f, N_SRC, blockIdx.x * 64);
    else
      gemm_body<false>(A, Bs, bias_s, w_comb, (void*)self0, score_f, N_DST,
                       (blockIdx.x - NB_BIG) * 64);
    asm volatile("" ::: "memory");
  }
}

// ---------------------------------------------------------------------------
// attn (R5 body, REP-wrapped)
// ---------------------------------------------------------------------------
__global__ __launch_bounds__(256, 4) void attn_kernel(
    const float* __restrict__ labels, const float* __restrict__ labels_ori,
    const float* __restrict__ label_rela, const int* __restrict__ nbr_idx,
    const ushort* __restrict__ hsrc, const float* __restrict__ self0,
    const float* __restrict__ score_f, const float* __restrict__ eps_p,
    const float* __restrict__ out_bias, float* __restrict__ out) {
  const int t = threadIdx.x;
  const int wv = t >> 6, ln = t & 63;
  const int n = blockIdx.x * 4 + wv;
  const int dg = ln & 15, kg = ln >> 4;

  const float eps = eps_p[0];
  const float om = 1.f - eps;

#pragma unroll 1
  for (int rep = 0; rep < REP_ATTN; ++rep) {
    float va = 0.f;
    if (dg < LDIM) {
#pragma unroll
      for (int b = 0; b < LDIM; ++b)
        va += label_rela[dg * LDIM + b] * labels[(size_t)n * LDIM + b];
      va *= eps;
    }

    const int* irow = nbr_idx + (size_t)n * KNBR;
    int ids[8];
    uint4 hv[8];
#pragma unroll
    for (int j = 0; j < 8; ++j) {
      ids[j] = irow[kg * 8 + j];
      hv[j] = *(const uint4*)(hsrc + (size_t)ids[j] * OUT_F + dg * 8);
    }
    float m[8];
#pragma unroll
    for (int j = 0; j < 8; ++j) {
      float sp = 0.f;
      if (dg == 0) sp = om * score_f[ids[j]];
      if (dg < LDIM) sp = fmaf(labels[(size_t)ids[j] * LDIM + dg], va, sp);
      m[j] = sp;
    }
#pragma unroll
    for (int s = 1; s < 16; s <<= 1) {
#pragma unroll
      for (int j = 0; j < 8; ++j) m[j] += __shfl_xor(m[j], s);
    }
    float mx = m[0];
#pragma unroll
    for (int j = 1; j < 8; ++j) mx = fmaxf(mx, m[j]);
    mx = fmaxf(mx, __shfl_xor(mx, 16));
    mx = fmaxf(mx, __shfl_xor(mx, 32));
    float ssum = 0.f;
#pragma unroll
    for (int j = 0; j < 8; ++j) {
      m[j] = __expf(m[j] - mx);
      ssum += m[j];
    }
    ssum += __shfl_xor(ssum, 16);
    ssum += __shfl_xor(ssum, 32);
    const float scale = 1.f / (ssum * (float)KNBR);
    float pn[8];
#pragma unroll
    for (int e = 0; e < 8; ++e) pn[e] = 0.f;
#pragma unroll
    for (int j = 0; j < 8; ++j) {
      float a = m[j];
      float hfj[8];
      unpack8(hv[j], hfj);
#pragma unroll
      for (int e = 0; e < 8; ++e) pn[e] = fmaf(a, hfj[e], pn[e]);
    }
#pragma unroll
    for (int e = 0; e < 8; ++e) {
      pn[e] += __shfl_xor(pn[e], 16);
      pn[e] += __shfl_xor(pn[e], 32);
    }
    if (kg == 0) {
      const float* srow = self0 + (size_t)n * OUT_F + dg * 8;
      float* orow = out + (size_t)n * OUT_F + dg * 8;
      f32x4 o0, o1;
#pragma unroll
      for (int e = 0; e < 4; ++e)
        o0[e] = (srow[e] + pn[e] * scale) * 0.5f + out_bias[dg * 8 + e];
#pragma unroll
      for (int e = 0; e < 4; ++e)
        o1[e] = (srow[4 + e] + pn[4 + e] * scale) * 0.5f + out_bias[dg * 8 + 4 + e];
      *(f32x4*)orow = o0;
      *(f32x4*)(orow + 4) = o1;
    }
    if (kg == 1 && dg < LDIM)
      out[OUT_CENT + (size_t)n * LDIM + dg] = labels[(size_t)n * LDIM + dg];
    if (kg == 2 && dg < LDIM)
      out[OUT_LORI + (size_t)n * LDIM + dg] = labels_ori[(size_t)n * LDIM + dg];
    asm volatile("" ::: "memory");
  }
}

// ---------------------------------------------------------------------------
extern "C" void kernel_launch(void* const* d_in, const int* in_sizes, int n_in,
                              void* d_out, int out_size, void* d_ws, size_t ws_size,
                              hipStream_t stream) {
  const float* feat       = (const float*)d_in[0];
  const float* labels     = (const float*)d_in[1];
  const float* labels_ori = (const float*)d_in[2];
  const float* label_rela = (const float*)d_in[3];
  const float* W_neigh    = (const float*)d_in[4];
  const float* b_neigh    = (const float*)d_in[5];
  const float* W_self     = (const float*)d_in[6];
  const float* b_self     = (const float*)d_in[7];
  const float* W_attn     = (const float*)d_in[8];
  // d_in[9] = b_attn (constant under softmax -> unused)
  const float* fW         = (const float*)d_in[10];
  const float* eps        = (const float*)d_in[11];
  const float* out_bias   = (const float*)d_in[12];
  const int*   nbr_idx    = (const int*)d_in[13];

  float* wsf = (float*)d_ws;
  float* out = (float*)d_out;

  float*  w_comb  = wsf + WS_WCOMB;
  ushort* Bn      = (ushort*)(wsf + WS_BN);
  ushort* Bsf     = (ushort*)(wsf + WS_BS);
  ushort* h_src   = (ushort*)(wsf + WS_HSRC);
  float*  self0   = wsf + WS_SELF0;
  float*  score_f = wsf + WS_SCORE;

  prep_kernel<<<384, 256, 0, stream>>>(W_attn, fW, W_neigh, W_self, w_comb, Bn, Bsf);
  fused_gemm<<<NB_BIG + NB_SELF, 256, 0, stream>>>(feat, Bn, Bsf, b_neigh, b_self,
                                                   w_comb, h_src, self0, score_f);
  attn_kernel<<<(N_DST / 4), 256, 0, stream>>>(labels, labels_ori, label_rela, nbr_idx,
                                               h_src, self0, score_f, eps, out_bias, out);
}

// Round 11
// 61.035 us; speedup vs baseline: 5.0820x; 5.0820x over previous
//
#include <hip/hip_runtime.h>
#include <hip/hip_bf16.h>

#define N_SRC 50000
#define N_DST 10000
#define KNBR  32
#define IN_F  256
#define OUT_F 128
#define LDIM  10
#define ATTN_OUT 1024
#define NB_BIG  782   // ceil(50000/64); first ceil(10000/64) blocks also do the self GEMM

using f32x4 = __attribute__((ext_vector_type(4))) float;
using s16x8 = __attribute__((ext_vector_type(8))) short;

// Output layout (floats): rst (N_DST*128) | cent_l (N_DST*10) | labels_ori[:N_DST] (N_DST*10)
#define OUT_CENT (N_DST*OUT_F)
#define OUT_LORI (N_DST*OUT_F + N_DST*LDIM)

// Workspace float offsets
#define WS_WCOMB 0                                   // 128 floats
#define WS_BN    128                                 // 32768 ushort
#define WS_BS    (128 + 16384)                       // 32768 ushort
#define WS_HSRC  (128 + 32768)                       // N_SRC*128 ushort
#define WS_SELF0 (WS_HSRC + (N_SRC*OUT_F/2))         // N_DST*128 floats
#define WS_SCORE (WS_SELF0 + N_DST*OUT_F)            // N_SRC floats

__device__ __forceinline__ ushort f2bf(float x) {
  __hip_bfloat16 h = __float2bfloat16(x);
  return *reinterpret_cast<ushort*>(&h);
}

__device__ __forceinline__ void unpack8(uint4 hv, float* o) {
  o[0] = __uint_as_float(hv.x << 16);
  o[1] = __uint_as_float(hv.x & 0xffff0000u);
  o[2] = __uint_as_float(hv.y << 16);
  o[3] = __uint_as_float(hv.y & 0xffff0000u);
  o[4] = __uint_as_float(hv.z << 16);
  o[5] = __uint_as_float(hv.z & 0xffff0000u);
  o[6] = __uint_as_float(hv.w << 16);
  o[7] = __uint_as_float(hv.w & 0xffff0000u);
}

// ---------------------------------------------------------------------------
// prep (R5 exact): blocks 0..127 w_comb | 128..255 W_neigh->bf16 | 256..383 W_self
// ---------------------------------------------------------------------------
__global__ __launch_bounds__(256) void prep_kernel(
    const float* __restrict__ W_attn, const float* __restrict__ fW,
    const float* __restrict__ W_neigh, const float* __restrict__ W_self,
    float* __restrict__ w_comb, ushort* __restrict__ Bn, ushort* __restrict__ Bs) {
  const int b = blockIdx.x;
  const int t = threadIdx.x;
  if (b < 128) {
    __shared__ float red[256];
    float s = 0.f;
#pragma unroll
    for (int i = 0; i < 4; ++i) {
      int o = t + i * 256;
      s += W_attn[(size_t)b * ATTN_OUT + o] * fW[o];
    }
    red[t] = s;
    __syncthreads();
    for (int st = 128; st > 0; st >>= 1) {
      if (t < st) red[t] += red[t + st];
      __syncthreads();
    }
    if (t == 0) w_comb[b] = red[0];
  } else if (b < 256) {
    int k = 2 * (b - 128) + (t >> 7);
    int n = t & 127;
    Bn[(k >> 3) * 1024 + n * 8 + (k & 7)] = f2bf(W_neigh[(size_t)k * OUT_F + n]);
  } else {
    int k = 2 * (b - 256) + (t >> 7);
    int n = t & 127;
    Bs[(k >> 3) * 1024 + n * 8 + (k & 7)] = f2bf(W_self[(size_t)k * OUT_F + n]);
  }
}

// ---------------------------------------------------------------------------
// GEMM with coalesced LDS A-staging.
//   Stage: per wave, each load instr covers ONE full 1 KB fp32 row (64 lanes x
//   16 B contiguous) -> DRAM-efficient bursts. cvt to bf16, ds_write to a
//   32 KB XOR-swizzled tile (idx ^ ((row&7)<<3), same involution on read).
//   Compute: ds_read_b128 A-frags; B-frags streamed from L2-resident table.
//   Blocks with m0 < N_DST run a second MFMA pass for the self GEMM (A staged
//   once, duplicate 10 MB read eliminated).
// ---------------------------------------------------------------------------
__global__ __launch_bounds__(256, 3) void fused_gemm(
    const float* __restrict__ A,
    const ushort* __restrict__ Bn, const ushort* __restrict__ Bs,
    const float* __restrict__ bias_n, const float* __restrict__ bias_s,
    const float* __restrict__ w_comb,
    ushort* __restrict__ hsrc, float* __restrict__ self0, float* __restrict__ score_f) {
  __shared__ ushort A_lds[64 * 256];   // 32 KB bf16 tile, swizzled
  const int t = threadIdx.x;
  const int wv = t >> 6, ln = t & 63;
  const int dg = ln & 15, kg = ln >> 4;
  const int m0 = blockIdx.x * 64;

  // ---- Stage A (2 batches x 8 wave-contiguous 1 KB row loads) ----
#pragma unroll
  for (int batch = 0; batch < 2; ++batch) {
    f32x4 v[8];
#pragma unroll
    for (int j = 0; j < 8; ++j) {
      int row = (batch * 8 + j) * 4 + wv;        // 0..63
      int gr = m0 + row;
      gr = gr < N_SRC ? gr : N_SRC - 1;          // clamp: load always valid
      v[j] = *(const f32x4*)&A[(size_t)gr * IN_F + 4 * ln];
    }
#pragma unroll
    for (int j = 0; j < 8; ++j) {
      int row = (batch * 8 + j) * 4 + wv;
      short4 s4;
      s4.x = (short)f2bf(v[j][0]); s4.y = (short)f2bf(v[j][1]);
      s4.z = (short)f2bf(v[j][2]); s4.w = (short)f2bf(v[j][3]);
      int idx = (row * 256 + 4 * ln) ^ ((row & 7) << 3);
      *(short4*)&A_lds[idx] = s4;
    }
  }
  __syncthreads();

  // ---- A fragments from LDS ----
  const int rowf = wv * 16 + dg;                 // this lane's fragment row
  s16x8 afr[8];
#pragma unroll
  for (int k0 = 0; k0 < 8; ++k0) {
    int idx = (rowf * 256 + k0 * 32 + kg * 8) ^ ((dg & 7) << 3);
    afr[k0] = *(const s16x8*)&A_lds[idx];
  }

  // ---- Neigh MFMA pass ----
  f32x4 acc[8];
#pragma unroll
  for (int ct = 0; ct < 8; ++ct) acc[ct] = (f32x4){0.f, 0.f, 0.f, 0.f};
#pragma unroll
  for (int k0 = 0; k0 < 8; ++k0) {
    const ushort* bb = Bn + (k0 * 4 + kg) * 1024 + dg * 8;
#pragma unroll
    for (int ct = 0; ct < 8; ++ct) {
      s16x8 bfr = *reinterpret_cast<const s16x8*>(bb + ct * 128);
      acc[ct] = __builtin_amdgcn_mfma_f32_16x16x32_bf16(afr[k0], bfr, acc[ct], 0, 0, 0);
    }
  }

  // Epilogue. D layout: col = ct*16+dg, row = m0+wv*16+kg*4+e (HW-verified m89).
  float sc[4] = {0.f, 0.f, 0.f, 0.f};
#pragma unroll
  for (int ct = 0; ct < 8; ++ct) {
    int col = ct * 16 + dg;
    float bb = bias_n[col];
    float wc = w_comb[col];
#pragma unroll
    for (int e = 0; e < 4; ++e) {
      int rr = m0 + wv * 16 + kg * 4 + e;
      float v = acc[ct][e] + bb;
      sc[e] = fmaf(fmaxf(v, 0.1f * v), wc, sc[e]);
      if (rr < N_SRC) hsrc[(size_t)rr * OUT_F + col] = f2bf(v);
    }
  }
#pragma unroll
  for (int s = 1; s < 16; s <<= 1) {
#pragma unroll
    for (int e = 0; e < 4; ++e) sc[e] += __shfl_xor(sc[e], s);
  }
  if (dg == 0) {
#pragma unroll
    for (int e = 0; e < 4; ++e) {
      int rr = m0 + wv * 16 + kg * 4 + e;
      if (rr < N_SRC) score_f[rr] = sc[e];
    }
  }

  // ---- Self MFMA pass (first 157 blocks only; A already staged) ----
  if (m0 < N_DST) {
    f32x4 acc2[8];
#pragma unroll
    for (int ct = 0; ct < 8; ++ct) acc2[ct] = (f32x4){0.f, 0.f, 0.f, 0.f};
#pragma unroll
    for (int k0 = 0; k0 < 8; ++k0) {
      const ushort* bb = Bs + (k0 * 4 + kg) * 1024 + dg * 8;
#pragma unroll
      for (int ct = 0; ct < 8; ++ct) {
        s16x8 bfr = *reinterpret_cast<const s16x8*>(bb + ct * 128);
        acc2[ct] = __builtin_amdgcn_mfma_f32_16x16x32_bf16(afr[k0], bfr, acc2[ct], 0, 0, 0);
      }
    }
#pragma unroll
    for (int ct = 0; ct < 8; ++ct) {
      int col = ct * 16 + dg;
      float bb = bias_s[col];
#pragma unroll
      for (int e = 0; e < 4; ++e) {
        int rr = m0 + wv * 16 + kg * 4 + e;
        if (rr < N_DST) self0[(size_t)rr * OUT_F + col] = acc2[ct][e] + bb;
      }
    }
  }
}

// ---------------------------------------------------------------------------
// attn (R5 exact): one wave per dst node; score gathered from score_f; packed
// h gathers feed only PV.
// ---------------------------------------------------------------------------
__global__ __launch_bounds__(256, 4) void attn_kernel(
    const float* __restrict__ labels, const float* __restrict__ labels_ori,
    const float* __restrict__ label_rela, const int* __restrict__ nbr_idx,
    const ushort* __restrict__ hsrc, const float* __restrict__ self0,
    const float* __restrict__ score_f, const float* __restrict__ eps_p,
    const float* __restrict__ out_bias, float* __restrict__ out) {
  const int t = threadIdx.x;
  const int wv = t >> 6, ln = t & 63;
  const int n = blockIdx.x * 4 + wv;
  const int dg = ln & 15, kg = ln >> 4;

  const float eps = eps_p[0];
  const float om = 1.f - eps;

  float va = 0.f;
  if (dg < LDIM) {
#pragma unroll
    for (int b = 0; b < LDIM; ++b)
      va += label_rela[dg * LDIM + b] * labels[(size_t)n * LDIM + b];
    va *= eps;
  }

  const int* irow = nbr_idx + (size_t)n * KNBR;
  int ids[8];
  uint4 hv[8];
#pragma unroll
  for (int j = 0; j < 8; ++j) {
    ids[j] = irow[kg * 8 + j];
    hv[j] = *(const uint4*)(hsrc + (size_t)ids[j] * OUT_F + dg * 8);
  }
  float m[8];
#pragma unroll
  for (int j = 0; j < 8; ++j) {
    float sp = 0.f;
    if (dg == 0) sp = om * score_f[ids[j]];
    if (dg < LDIM) sp = fmaf(labels[(size_t)ids[j] * LDIM + dg], va, sp);
    m[j] = sp;
  }
#pragma unroll
  for (int s = 1; s < 16; s <<= 1) {
#pragma unroll
    for (int j = 0; j < 8; ++j) m[j] += __shfl_xor(m[j], s);
  }
  float mx = m[0];
#pragma unroll
  for (int j = 1; j < 8; ++j) mx = fmaxf(mx, m[j]);
  mx = fmaxf(mx, __shfl_xor(mx, 16));
  mx = fmaxf(mx, __shfl_xor(mx, 32));
  float ssum = 0.f;
#pragma unroll
  for (int j = 0; j < 8; ++j) {
    m[j] = __expf(m[j] - mx);
    ssum += m[j];
  }
  ssum += __shfl_xor(ssum, 16);
  ssum += __shfl_xor(ssum, 32);
  const float scale = 1.f / (ssum * (float)KNBR);
  float pn[8];
#pragma unroll
  for (int e = 0; e < 8; ++e) pn[e] = 0.f;
#pragma unroll
  for (int j = 0; j < 8; ++j) {
    float a = m[j];
    float hfj[8];
    unpack8(hv[j], hfj);
#pragma unroll
    for (int e = 0; e < 8; ++e) pn[e] = fmaf(a, hfj[e], pn[e]);
  }
#pragma unroll
  for (int e = 0; e < 8; ++e) {
    pn[e] += __shfl_xor(pn[e], 16);
    pn[e] += __shfl_xor(pn[e], 32);
  }
  if (kg == 0) {
    const float* srow = self0 + (size_t)n * OUT_F + dg * 8;
    float* orow = out + (size_t)n * OUT_F + dg * 8;
    f32x4 o0, o1;
#pragma unroll
    for (int e = 0; e < 4; ++e)
      o0[e] = (srow[e] + pn[e] * scale) * 0.5f + out_bias[dg * 8 + e];
#pragma unroll
    for (int e = 0; e < 4; ++e)
      o1[e] = (srow[4 + e] + pn[4 + e] * scale) * 0.5f + out_bias[dg * 8 + 4 + e];
    *(f32x4*)orow = o0;
    *(f32x4*)(orow + 4) = o1;
  }
  if (kg == 1 && dg < LDIM)
    out[OUT_CENT + (size_t)n * LDIM + dg] = labels[(size_t)n * LDIM + dg];
  if (kg == 2 && dg < LDIM)
    out[OUT_LORI + (size_t)n * LDIM + dg] = labels_ori[(size_t)n * LDIM + dg];
}

// ---------------------------------------------------------------------------
extern "C" void kernel_launch(void* const* d_in, const int* in_sizes, int n_in,
                              void* d_out, int out_size, void* d_ws, size_t ws_size,
                              hipStream_t stream) {
  const float* feat       = (const float*)d_in[0];
  const float* labels     = (const float*)d_in[1];
  const float* labels_ori = (const float*)d_in[2];
  const float* label_rela = (const float*)d_in[3];
  const float* W_neigh    = (const float*)d_in[4];
  const float* b_neigh    = (const float*)d_in[5];
  const float* W_self     = (const float*)d_in[6];
  const float* b_self     = (const float*)d_in[7];
  const float* W_attn     = (const float*)d_in[8];
  // d_in[9] = b_attn (constant under softmax -> unused)
  const float* fW         = (const float*)d_in[10];
  const float* eps        = (const float*)d_in[11];
  const float* out_bias   = (const float*)d_in[12];
  const int*   nbr_idx    = (const int*)d_in[13];

  float* wsf = (float*)d_ws;
  float* out = (float*)d_out;

  float*  w_comb  = wsf + WS_WCOMB;
  ushort* Bn      = (ushort*)(wsf + WS_BN);
  ushort* Bsf     = (ushort*)(wsf + WS_BS);
  ushort* h_src   = (ushort*)(wsf + WS_HSRC);
  float*  self0   = wsf + WS_SELF0;
  float*  score_f = wsf + WS_SCORE;

  prep_kernel<<<384, 256, 0, stream>>>(W_attn, fW, W_neigh, W_self, w_comb, Bn, Bsf);
  fused_gemm<<<NB_BIG, 256, 0, stream>>>(feat, Bn, Bsf, b_neigh, b_self,
                                         w_comb, h_src, self0, score_f);
  attn_kernel<<<(N_DST / 4), 256, 0, stream>>>(labels, labels_ori, label_rela, nbr_idx,
                                               h_src, self0, score_f, eps, out_bias, out);
}